// Round 7
// baseline (422.316 us; speedup 1.0000x reference)
//
#include <hip/hip_runtime.h>

// Problem constants (fixed by the reference)
#define T_SEQ   4096
#define BATCH   32
#define DIM     512
#define MROWS   (T_SEQ * BATCH)          // 131072 GEMM rows
#define S_STRIDE (BATCH * DIM)           // 16384 elements per time step
#define OUT_ELEMS ((size_t)T_SEQ * BATCH * DIM)   // 67108864
#define NCH     32                        // T-chunks for parallel scan
#define CLEN    (T_SEQ / NCH)             // 128 steps per chunk
#define NCHAIN  (BATCH * DIM)             // 16384 independent chains

// persistent full-N GEMM: Mtile=128, N=512, BK=64; 256 blocks x 4 M-tiles
#define NSTEP   32                        // 4 M-tiles x 8 K-steps
// LDS regions in shorts: A 128x64, B 512x64, double-buffered = 160 KB total
#define A0S     0
#define A1S     8192
#define B0S     16384
#define B1S     49152
#define GLDS_B  163840

typedef __bf16 bf8_t __attribute__((ext_vector_type(8)));
typedef float  f4_t  __attribute__((ext_vector_type(4)));
typedef unsigned short u16x8 __attribute__((ext_vector_type(8)));
typedef __attribute__((address_space(1))) void gvoid_t;
typedef __attribute__((address_space(3))) void lvoid_t;

__device__ __forceinline__ unsigned short f2bf(float f) {
    unsigned int u = __float_as_uint(f);
    u += 0x7FFFu + ((u >> 16) & 1u);     // round-to-nearest-even
    return (unsigned short)(u >> 16);
}
__device__ __forceinline__ float bf2f(unsigned short b) {
    return __uint_as_float(((unsigned int)b) << 16);
}

#define VMC(n)  asm volatile("s_waitcnt vmcnt(" #n ")" ::: "memory")
#define LGKM0   asm volatile("s_waitcnt lgkmcnt(0)" ::: "memory")

// ---------------- f32 -> bf16 convert (weights only) -----------------
__global__ __launch_bounds__(256) void k_cvt(const float* __restrict__ in,
                                             unsigned short* __restrict__ out) {
    size_t i = ((size_t)blockIdx.x * 256 + threadIdx.x) * 8;
    float4 a = *reinterpret_cast<const float4*>(in + i);
    float4 b = *reinterpret_cast<const float4*>(in + i + 4);
    u16x8 o;
    o[0] = f2bf(a.x); o[1] = f2bf(a.y); o[2] = f2bf(a.z); o[3] = f2bf(a.w);
    o[4] = f2bf(b.x); o[5] = f2bf(b.y); o[6] = f2bf(b.z); o[7] = f2bf(b.w);
    *reinterpret_cast<u16x8*>(out + i) = o;
}

// ---------------- persistent full-N bf16 GEMM  C = A * B^T ------------
// 256 blocks (1/CU), 512 threads (8 waves, wave = 128x64 of the 128x512 tile).
// Per K-step: {24 ds_read + 64 MFMA} bar {stage s+2 (10 gll), vmcnt(10)} bar.
// Stages lead consumption by 2 steps (~2000 cy). A read once (full-N block).
// XOR swizzle: 16B slot sl of row r stored at sl^(r&7); gll sources
// pre-inverse-swizzled; reads apply the same XOR (bank-conflict-free).
// AF32=1: A f32 -> regs (ping-pong afP/afQ), cvt + swizzled ds_write of tile
// s+1 during step s's stage section (region last read at s-1: hazard-free).
template <int AF32>
__global__ __launch_bounds__(512, 2)
void k_gemm_fn(const void* __restrict__ Ap,
               const unsigned short* __restrict__ Bp,
               unsigned short* __restrict__ C) {
    extern __shared__ unsigned short lds[];   // 81920 shorts = 160 KB

    const int tid  = threadIdx.x;
    const int lane = tid & 63;
    const int wv   = tid >> 6;            // wave 0..7 -> N-slice wv*64
    const int l15  = lane & 15;
    const int l16  = lane >> 4;
    const int lj   = lane >> 3;           // staging row-within-8 (= r&7)
    const int ss8  = lane & 7;            // staging 16B slot
    const int mbase = blockIdx.x * 4;     // M-tiles mbase..mbase+3

    const unsigned short* Ab = (const unsigned short*)Ap;
    const float*          Af = (const float*)Ap;

    auto stageB = [&](int reg, int kt) {  // 8 gll: rows 0..511 of B
#pragma unroll
        for (int j = 0; j < 8; ++j) {
            const int r = j * 64 + wv * 8 + lj;
            const unsigned short* src = Bp + (size_t)r * 512 + kt * 64 + (ss8 ^ lj) * 8;
            unsigned short* dst = &lds[reg + (j * 64 + wv * 8) * 64];
            __builtin_amdgcn_global_load_lds((gvoid_t*)src, (lvoid_t*)dst, 16, 0, 0);
        }
    };
    auto stageA = [&](int reg, int kt, size_t gm) {  // 2 gll: rows 0..127
#pragma unroll
        for (int j = 0; j < 2; ++j) {
            const int r = j * 64 + wv * 8 + lj;
            const unsigned short* src = Ab + (gm + r) * 512 + kt * 64 + (ss8 ^ lj) * 8;
            unsigned short* dst = &lds[reg + (j * 64 + wv * 8) * 64];
            __builtin_amdgcn_global_load_lds((gvoid_t*)src, (lvoid_t*)dst, 16, 0, 0);
        }
    };
    // ---- f32-A reg staging (gemm1): thread -> row tid/4, 16-float segment ----
    const int ra = tid >> 2, sg = tid & 3;
    auto loadAf = [&](float4* h, int kt, size_t gm) {   // 4 loads
        const float* src = Af + (gm + ra) * 512 + kt * 64 + sg * 16;
#pragma unroll
        for (int q = 0; q < 4; ++q) h[q] = *reinterpret_cast<const float4*>(src + q * 4);
    };
    auto writeAf = [&](int reg, const float4* h) {      // 2 swizzled ds_write_b128
        u16x8 o0, o1;
        o0[0] = f2bf(h[0].x); o0[1] = f2bf(h[0].y); o0[2] = f2bf(h[0].z); o0[3] = f2bf(h[0].w);
        o0[4] = f2bf(h[1].x); o0[5] = f2bf(h[1].y); o0[6] = f2bf(h[1].z); o0[7] = f2bf(h[1].w);
        o1[0] = f2bf(h[2].x); o1[1] = f2bf(h[2].y); o1[2] = f2bf(h[2].z); o1[3] = f2bf(h[2].w);
        o1[4] = f2bf(h[3].x); o1[5] = f2bf(h[3].y); o1[6] = f2bf(h[3].z); o1[7] = f2bf(h[3].w);
        const int sl0 = (sg * 2) ^ (ra & 7), sl1 = (sg * 2 + 1) ^ (ra & 7);
        *reinterpret_cast<u16x8*>(&lds[reg + ra * 64 + sl0 * 8]) = o0;
        *reinterpret_cast<u16x8*>(&lds[reg + ra * 64 + sl1 * 8]) = o1;
    };

    f4_t  acc[8][4] = {};
    float4 afP[4], afQ[4];     // ping-pong in-flight f32 A (AF32 only)

    // ================= prologue: K-steps 0 and 1 =================
    if constexpr (AF32) {
        loadAf(afP, 0, (size_t)mbase * 128);   // tile step 0
        stageB(B0S, 0);
        loadAf(afQ, 1, (size_t)mbase * 128);   // tile step 1
        stageB(B1S, 1);
        VMC(20);                               // afP landed
        writeAf(A0S, afP);
        LGKM0; __builtin_amdgcn_sched_barrier(0);
        VMC(12);                               // B(0) landed
    } else {
        stageA(A0S, 0, (size_t)mbase * 128);
        stageB(B0S, 0);
        stageA(A1S, 1, (size_t)mbase * 128);
        stageB(B1S, 1);
        VMC(10);                               // step-0 A+B landed
    }
    __builtin_amdgcn_s_barrier();

    // ================= main loop: 32 K-steps =================
#pragma unroll 2
    for (int s = 0; s < NSTEP; ++s) {
        const int Ar = (s & 1) ? A1S : A0S;
        const int Br = (s & 1) ? B1S : B0S;

        // ---- compute: 24 ds_read + 64 MFMA (compiler-scheduled lgkm) ----
        bf8_t bb[4][2];
#pragma unroll
        for (int n = 0; n < 4; ++n)
#pragma unroll
            for (int ks = 0; ks < 2; ++ks) {
                const int c  = wv * 64 + n * 16 + l15;
                const int sl = (ks * 4 + l16) ^ (l15 & 7);
                bb[n][ks] = *reinterpret_cast<const bf8_t*>(
                    (const char*)&lds[Br] + (size_t)c * 128 + sl * 16);
            }
#pragma unroll
        for (int mh = 0; mh < 2; ++mh) {
            bf8_t af[4][2];
#pragma unroll
            for (int m = 0; m < 4; ++m)
#pragma unroll
                for (int ks = 0; ks < 2; ++ks) {
                    const int r  = (mh * 4 + m) * 16 + l15;
                    const int sl = (ks * 4 + l16) ^ (l15 & 7);
                    af[m][ks] = *reinterpret_cast<const bf8_t*>(
                        (const char*)&lds[Ar] + (size_t)r * 128 + sl * 16);
                }
#pragma unroll
            for (int m = 0; m < 4; ++m)
#pragma unroll
                for (int n = 0; n < 4; ++n)
#pragma unroll
                    for (int ks = 0; ks < 2; ++ks)
                        acc[mh * 4 + m][n] = __builtin_amdgcn_mfma_f32_16x16x32_bf16(
                            af[m][ks], bb[n][ks], acc[mh * 4 + m][n], 0, 0, 0);
        }
        __builtin_amdgcn_s_barrier();   // all reads of [s&1] regions done

        // ---- stage section: issue s+2, wait s-1 (2-step lead) ----
        const int s2 = s + 2;
        if (s2 < NSTEP) {
            const int    kt2 = s2 & 7;
            const size_t gm2 = (size_t)(mbase + (s2 >> 3)) * 128;
            if constexpr (AF32) {
                if (s & 1) loadAf(afQ, kt2, gm2); else loadAf(afP, kt2, gm2);
                stageB(Br, kt2);
                VMC(12);                           // s-1's Af + B landed
                // write tile s+1 into the OTHER A region (last read at s-1)
                if (s & 1) writeAf(A0S, afP); else writeAf(A1S, afQ);
                LGKM0; __builtin_amdgcn_sched_barrier(0);
            } else {
                stageA(Ar, kt2, gm2);
                stageB(Br, kt2);
                VMC(10);                           // s-1's stages landed
            }
        } else if (s == NSTEP - 2) {               // s = 30 (even)
            if constexpr (AF32) {
                VMC(8);                            // afQ (tile 31) landed
                writeAf(A1S, afQ);
                LGKM0; __builtin_amdgcn_sched_barrier(0);
            }
            VMC(0);                                // B(31) landed for s=31
        }
        __builtin_amdgcn_s_barrier();   // publish stages + A-writes

        // ---- per-M-tile epilogue: write C, reset acc ----
        if ((s & 7) == 7) {
            const size_t gmt  = (size_t)(mbase + (s >> 3)) * 128;
            const int    crow0 = l16 * 4;
#pragma unroll
            for (int m = 0; m < 8; ++m)
#pragma unroll
                for (int n = 0; n < 4; ++n) {
                    const size_t row0 = gmt + m * 16 + crow0;
                    const int    col  = wv * 64 + n * 16 + l15;
#pragma unroll
                    for (int r = 0; r < 4; ++r)
                        C[(row0 + r) * 512 + col] = f2bf(acc[m][n][r]);
                    acc[m][n] = (f4_t){0.f, 0.f, 0.f, 0.f};
                }
        }
    }
}

// ------------- chunk-parallel scan, pass 1: per-chunk (A,B) summaries -------
__global__ __launch_bounds__(256)
void k_scan_p1(const unsigned short* __restrict__ q,
               const float* __restrict__ w_hh,
               const float* __restrict__ b_ih,
               float* __restrict__ Asum,
               float* __restrict__ Bsum) {
    const int g = (blockIdx.x & 63) * 256 + threadIdx.x;
    const int c = blockIdx.x >> 6;
    const float w  = w_hh[g & 511];
    const float bs = b_ih[g & 511];
    const unsigned short* p = q + (size_t)c * CLEN * S_STRIDE + g;

    float A = 0.f, Bv = 0.f;
    float s0[8], s1[8];
#pragma unroll
    for (int j = 0; j < 8; ++j) s0[j] = bf2f(p[(size_t)j * S_STRIDE]);
#pragma unroll
    for (int j = 0; j < 8; ++j) s1[j] = bf2f(p[(size_t)(8 + j) * S_STRIDE]);

    for (int j0 = 0; j0 < CLEN; j0 += 16) {
#pragma unroll
        for (int j = 0; j < 8; ++j) {
            float qv = s0[j] + bs;
            A  = fmaxf(fmaf(w, A, qv), 0.f);
            Bv = fmaf(w, Bv, qv);
        }
        if (j0 + 16 < CLEN) {
#pragma unroll
            for (int j = 0; j < 8; ++j) s0[j] = bf2f(p[(size_t)(j0 + 16 + j) * S_STRIDE]);
        }
#pragma unroll
        for (int j = 0; j < 8; ++j) {
            float qv = s1[j] + bs;
            A  = fmaxf(fmaf(w, A, qv), 0.f);
            Bv = fmaf(w, Bv, qv);
        }
        if (j0 + 24 < CLEN) {
#pragma unroll
            for (int j = 0; j < 8; ++j) s1[j] = bf2f(p[(size_t)(j0 + 24 + j) * S_STRIDE]);
        }
    }
    Asum[(size_t)c * NCHAIN + g] = A;
    Bsum[(size_t)c * NCHAIN + g] = Bv;
}

// ------------- pass 2: per-block stitch + exact replay ----------------------
template <int MODE>
__global__ __launch_bounds__(256)
void k_scan_p2(const unsigned short* __restrict__ q,
               const float* __restrict__ w_hh,
               const float* __restrict__ b_ih,
               const float* __restrict__ Asum,
               const float* __restrict__ Bsum,
               float* __restrict__ of32,
               unsigned short* __restrict__ ob16,
               float* __restrict__ hT) {
    const int g = (blockIdx.x & 63) * 256 + threadIdx.x;
    const int c = blockIdx.x >> 6;
    const float w  = w_hh[g & 511];
    const float bs = b_ih[g & 511];

    float cw = w;
#pragma unroll
    for (int i = 0; i < 7; ++i) cw *= cw;      // w^128
    float h = 0.f;
    for (int cc = 0; cc < c; ++cc)
        h = fmaxf(Asum[(size_t)cc * NCHAIN + g], fmaf(cw, h, Bsum[(size_t)cc * NCHAIN + g]));

    const size_t base = (size_t)c * CLEN * S_STRIDE + g;
    const unsigned short* p = q + base;

    float s0[8], s1[8];
#pragma unroll
    for (int j = 0; j < 8; ++j) s0[j] = bf2f(p[(size_t)j * S_STRIDE]);
#pragma unroll
    for (int j = 0; j < 8; ++j) s1[j] = bf2f(p[(size_t)(8 + j) * S_STRIDE]);

    for (int j0 = 0; j0 < CLEN; j0 += 16) {
#pragma unroll
        for (int j = 0; j < 8; ++j) {
            h = fmaxf(fmaf(w, h, s0[j] + bs), 0.f);
            const size_t idx = base + (size_t)(j0 + j) * S_STRIDE;
            if (MODE == 0) of32[idx] = h; else ob16[idx] = f2bf(h);
        }
        if (j0 + 16 < CLEN) {
#pragma unroll
            for (int j = 0; j < 8; ++j) s0[j] = bf2f(p[(size_t)(j0 + 16 + j) * S_STRIDE]);
        }
#pragma unroll
        for (int j = 0; j < 8; ++j) {
            h = fmaxf(fmaf(w, h, s1[j] + bs), 0.f);
            const size_t idx = base + (size_t)(j0 + 8 + j) * S_STRIDE;
            if (MODE == 0) of32[idx] = h; else ob16[idx] = f2bf(h);
        }
        if (j0 + 24 < CLEN) {
#pragma unroll
            for (int j = 0; j < 8; ++j) s1[j] = bf2f(p[(size_t)(j0 + 24 + j) * S_STRIDE]);
        }
    }
    if (c == NCH - 1) hT[g] = h;
}

extern "C" void kernel_launch(void* const* d_in, const int* in_sizes, int n_in,
                              void* d_out, int out_size, void* d_ws, size_t ws_size,
                              hipStream_t stream) {
    const float* x    = (const float*)d_in[0];   // (4096,32,512)
    const float* W_ih = (const float*)d_in[1];   // (2,512,512)
    const float* w_hh = (const float*)d_in[2];   // (2,512)
    const float* b_ih = (const float*)d_in[3];   // (2,512)

    // 160 KB dynamic LDS opt-in (idempotent; outside stream ops)
    hipFuncSetAttribute(reinterpret_cast<const void*>(&k_gemm_fn<1>),
                        hipFuncAttributeMaxDynamicSharedMemorySize, GLDS_B);
    hipFuncSetAttribute(reinterpret_cast<const void*>(&k_gemm_fn<0>),
                        hipFuncAttributeMaxDynamicSharedMemorySize, GLDS_B);

    // ---- workspace layout (~139 MB) ----
    unsigned short* proj2 = (unsigned short*)d_ws;                // 134 MB
    unsigned short* Wb    = proj2 + OUT_ELEMS;                    // 1 MB
    float* Asum = (float*)(Wb + 2 * 512 * 512);                   // 2 MB
    float* Bsum = Asum + (size_t)NCH * NCHAIN;                    // 2 MB

    // ---- d_out staging: proj1 (bf16) lower half, ys1 (bf16) upper half ----
    unsigned short* proj1 = (unsigned short*)d_out;
    unsigned short* ys1   = proj1 + OUT_ELEMS;
    float* out = (float*)d_out;
    float* hT  = out + OUT_ELEMS;                                 // h_n (2,32,512)

    const int sgrid = 64 * NCH;             // 2048 blocks for scan passes

    // 1. W -> bf16
    k_cvt<<<524288 / 8 / 256, 256, 0, stream>>>(W_ih, Wb);
    // 2. layer-0 GEMM (A = x f32, fused cvt) -> proj1
    k_gemm_fn<1><<<256, 512, GLDS_B, stream>>>(x, Wb, proj1);
    // 3-4. layer-0 chunked scan -> ys1 (bf16) + hT0
    k_scan_p1<<<sgrid, 256, 0, stream>>>(proj1, w_hh, b_ih, Asum, Bsum);
    k_scan_p2<1><<<sgrid, 256, 0, stream>>>(proj1, w_hh, b_ih, Asum, Bsum,
                                            nullptr, ys1, hT);
    // 5. layer-1 GEMM (A = ys1 bf16) -> proj2 (ws)
    k_gemm_fn<0><<<256, 512, GLDS_B, stream>>>(ys1, Wb + 512 * 512, proj2);
    // 6-7. layer-1 chunked scan -> final out (f32, overwrites proj1/ys1) + hT1
    k_scan_p1<<<sgrid, 256, 0, stream>>>(proj2, w_hh + DIM, b_ih + DIM, Asum, Bsum);
    k_scan_p2<0><<<sgrid, 256, 0, stream>>>(proj2, w_hh + DIM, b_ih + DIM, Asum, Bsum,
                                            out, nullptr, hT + NCHAIN);
}